// Round 1
// baseline (3965.822 us; speedup 1.0000x reference)
//
#include <hip/hip_runtime.h>
#include <math.h>

#define NPTS 16384
#define WWIN 2048
#define NWIN 7
#define KNB  16
#define CDIM 128
#define NTGT (NPTS - WWIN)   // 14336
#define FSTR 20              // padded row stride (floats) for [128][16] transposed tiles

// ---------------------------------------------------------------------------
// KNN: exact top-16 nearest context points per target.
// block: 256 threads = 8 scanners x 32 targets; grid: NWIN * 64 blocks.
// Context staged through LDS in 2048-point chunks; per-thread sorted top-16 in
// registers; 8-way sorted-list merge in LDS at the end.
// ---------------------------------------------------------------------------
__global__ __launch_bounds__(256, 4) void knn_kernel(const float4* __restrict__ bx,
                                                     int* __restrict__ idx_ws) {
  __shared__ float4 stage[2048];                // 32KB, overlaid with merge pairs
  float2* pairs = (float2*)stage;               // [32 tgt][8 scan][16] (d, idx)

  const int w    = blockIdx.x >> 6;             // window 0..6
  const int bg   = blockIdx.x & 63;             // target group within window
  const int cur  = WWIN * (w + 1);              // context length
  const int t    = threadIdx.x;
  const int s    = t >> 5;                      // scanner 0..7
  const int tl   = t & 31;                      // local target 0..31
  const int trow = cur + bg * 32 + tl;          // global target row

  const float4 tp = bx[trow];

  float sd[KNB];
  int   si[KNB];
#pragma unroll
  for (int q = 0; q < KNB; ++q) { sd[q] = 3.4e38f; si[q] = -1; }

  for (int ch = 0; ch <= w; ++ch) {
    __syncthreads();
    for (int q = t; q < 2048; q += 256) stage[q] = bx[ch * 2048 + q];
    __syncthreads();
    for (int j = s; j < 2048; j += 8) {
      const float4 cp = stage[j];
      const float dx = tp.x - cp.x, dy = tp.y - cp.y, dz = tp.z - cp.z;
      const float d2 = dx * dx + dy * dy + dz * dz;
      if (d2 < sd[KNB - 1]) {
        float cv = d2; int ci = ch * 2048 + j;
#pragma unroll
        for (int q = 0; q < KNB; ++q) {   // sorted insertion (carry chain)
          const bool lt = cv < sd[q];
          const float nv = lt ? cv : sd[q];
          const float xv = lt ? sd[q] : cv;
          const int   ni = lt ? ci : si[q];
          const int   xi = lt ? si[q] : ci;
          sd[q] = nv; si[q] = ni; cv = xv; ci = xi;
        }
      }
    }
  }
  __syncthreads();
#pragma unroll
  for (int q = 0; q < KNB; ++q)
    pairs[(tl * 8 + s) * KNB + q] = make_float2(sd[q], __int_as_float(si[q]));
  __syncthreads();

  if (t < 32) {   // 8-way merge of sorted lists for target t
    int h0 = 0, h1 = 0, h2 = 0, h3 = 0, h4 = 0, h5 = 0, h6 = 0, h7 = 0;
    const int slot = cur + bg * 32 + t - WWIN;
    const int base = t * 8 * KNB;
    for (int n = 0; n < KNB; ++n) {
      float best = 3.5e38f; int baddr = base; int bs = 0;
      {
        int hh, ad; float v;
#define TRY(S, H) hh = H; if (hh < KNB) { ad = base + (S)*KNB + hh; v = pairs[ad].x; \
                  if (v < best) { best = v; baddr = ad; bs = (S); } }
        TRY(0, h0) TRY(1, h1) TRY(2, h2) TRY(3, h3)
        TRY(4, h4) TRY(5, h5) TRY(6, h6) TRY(7, h7)
#undef TRY
      }
      idx_ws[slot * KNB + n] = __float_as_int(pairs[baddr].y);
      h0 += (bs == 0); h1 += (bs == 1); h2 += (bs == 2); h3 += (bs == 3);
      h4 += (bs == 4); h5 += (bs == 5); h6 += (bs == 6); h7 += (bs == 7);
    }
  }
}

// ---------------------------------------------------------------------------
// Per-target neighbor network. One block (256 thr = 4 waves) per target.
// f kept transposed in LDS: fT[channel][neighbor], row stride FSTR=20 floats.
// Thread (wave w, lane l) owns rows 4w..4w+3 and column pair (2l, 2l+1).
// ---------------------------------------------------------------------------
__device__ __forceinline__ void mm_acc(const float* __restrict__ src,
                                       const float* __restrict__ W,
                                       int rbase, int c0, float2 acc[4]) {
#pragma unroll 4
  for (int k = 0; k < CDIM; ++k) {
    const float4 fv = *(const float4*)(src + k * FSTR + rbase);
    const float2 wv = *(const float2*)(W + k * CDIM + c0);
    acc[0].x += fv.x * wv.x; acc[0].y += fv.x * wv.y;
    acc[1].x += fv.y * wv.x; acc[1].y += fv.y * wv.y;
    acc[2].x += fv.z * wv.x; acc[2].y += fv.z * wv.y;
    acc[3].x += fv.w * wv.x; acc[3].y += fv.w * wv.y;
  }
}

__device__ __forceinline__ void store_cols(float* __restrict__ dst, int rbase, int c0,
                                           const float2 acc[4]) {
  *(float4*)(dst + c0 * FSTR + rbase) =
      make_float4(acc[0].x, acc[1].x, acc[2].x, acc[3].x);
  *(float4*)(dst + (c0 + 1) * FSTR + rbase) =
      make_float4(acc[0].y, acc[1].y, acc[2].y, acc[3].y);
}

__global__ __launch_bounds__(256, 4) void nn_kernel(
    const float4* __restrict__ bx, const int* __restrict__ idx_ws,
    const float* __restrict__ attr_w, const float* __restrict__ attr_b,
    const float* __restrict__ pos_w1, const float* __restrict__ pos_b1,
    const float* __restrict__ pos_w2, const float* __restrict__ pos_b2,
    const float* __restrict__ wq, const float* __restrict__ wk,
    const float* __restrict__ wvp, const float* __restrict__ wout,
    const float* __restrict__ bout,
    const float* __restrict__ ms_w1, const float* __restrict__ ms_b1,
    const float* __restrict__ ms_w2, const float* __restrict__ ms_b2,
    const float* __restrict__ ms_w3, const float* __restrict__ ms_b3,
    float* __restrict__ out) {
  __shared__ float fT[CDIM * FSTR];
  __shared__ float bufA[CDIM * FSTR];
  __shared__ float bufB[CDIM * FSTR];
  __shared__ float sc[16 * FSTR];
  __shared__ float ggs[16 * 4];
  __shared__ float gas[16];
  __shared__ float featp[4 * CDIM];
  __shared__ float h1s[64];
  __shared__ float h2s[16];

  const int slot  = blockIdx.x;
  const int trow  = slot + WWIN;
  const int t     = threadIdx.x;
  const int wave  = t >> 6;
  const int lane  = t & 63;
  const int rbase = wave * 4;
  const int c0    = lane * 2;

  // ---- gather 16 neighbors, center, max-norm normalize ----
  if (t < 16) {
    const int nid  = idx_ws[slot * KNB + t];
    const float4 p = bx[nid];
    float sx = p.x, sy = p.y, sz = p.z;
#pragma unroll
    for (int m = 1; m < 16; m <<= 1) {
      sx += __shfl_xor(sx, m); sy += __shfl_xor(sy, m); sz += __shfl_xor(sz, m);
    }
    const float gx = p.x - sx * 0.0625f;
    const float gy = p.y - sy * 0.0625f;
    const float gz = p.z - sz * 0.0625f;
    float nr = sqrtf(gx * gx + gy * gy + gz * gz);
#pragma unroll
    for (int m = 1; m < 16; m <<= 1) nr = fmaxf(nr, __shfl_xor(nr, m));
    const float inv = 1.f / fmaxf(nr, 1e-8f);
    ggs[t * 4 + 0] = gx * inv; ggs[t * 4 + 1] = gy * inv;
    ggs[t * 4 + 2] = gz * inv; ggs[t * 4 + 3] = 0.f;
    gas[t] = p.w;
  }
  __syncthreads();

  // ---- pos hidden = relu(gg @ pos_w1 + b1) -> bufA ----
  {
    const float2 w1d0 = *(const float2*)(pos_w1 + 0 * CDIM + c0);
    const float2 w1d1 = *(const float2*)(pos_w1 + 1 * CDIM + c0);
    const float2 w1d2 = *(const float2*)(pos_w1 + 2 * CDIM + c0);
    const float2 b1v  = *(const float2*)(pos_b1 + c0);
    float2 hreg[4];
#pragma unroll
    for (int r = 0; r < 4; ++r) {
      const int i = rbase + r;
      const float gx = ggs[i * 4 + 0], gy = ggs[i * 4 + 1], gz = ggs[i * 4 + 2];
      const float hx = b1v.x + gx * w1d0.x + gy * w1d1.x + gz * w1d2.x;
      const float hy = b1v.y + gx * w1d0.y + gy * w1d1.y + gz * w1d2.y;
      hreg[r].x = fmaxf(hx, 0.f); hreg[r].y = fmaxf(hy, 0.f);
    }
    store_cols(bufA, rbase, c0, hreg);
  }
  __syncthreads();

  // ---- f = hidden @ pos_w2 + b2 + ga*attr_w + attr_b -> fT ----
  {
    float2 acc[4] = {{0, 0}, {0, 0}, {0, 0}, {0, 0}};
    mm_acc(bufA, pos_w2, rbase, c0, acc);
    const float2 b2v = *(const float2*)(pos_b2 + c0);
    const float2 awv = *(const float2*)(attr_w + c0);
    const float2 abv = *(const float2*)(attr_b + c0);
#pragma unroll
    for (int r = 0; r < 4; ++r) {
      const float ga = gas[rbase + r];
      acc[r].x += b2v.x + ga * awv.x + abv.x;
      acc[r].y += b2v.y + ga * awv.y + abv.y;
    }
    store_cols(fT, rbase, c0, acc);
  }
  __syncthreads();

  // ---- 5 attention layers ----
  const int i16 = t >> 4;
  const int j16 = t & 15;
  for (int l = 0; l < 5; ++l) {
    const float* Wq = wq + l * CDIM * CDIM;
    const float* Wk = wk + l * CDIM * CDIM;
    const float* Wv = wvp + l * CDIM * CDIM;
    {
      float2 acc[4] = {{0, 0}, {0, 0}, {0, 0}, {0, 0}};
      mm_acc(fT, Wq, rbase, c0, acc); store_cols(bufA, rbase, c0, acc);
    }
    {
      float2 acc[4] = {{0, 0}, {0, 0}, {0, 0}, {0, 0}};
      mm_acc(fT, Wk, rbase, c0, acc); store_cols(bufB, rbase, c0, acc);
    }
    __syncthreads();
    {
      // scores + softmax: one (i,j) pair per thread, row = 16-lane shfl group
      float sv = 0.f;
#pragma unroll 4
      for (int c = 0; c < CDIM; ++c) sv += bufA[c * FSTR + i16] * bufB[c * FSTR + j16];
      sv *= 0.08838834764831844055f;  // 1/sqrt(128)
      float mx = sv;
#pragma unroll
      for (int m = 1; m < 16; m <<= 1) mx = fmaxf(mx, __shfl_xor(mx, m));
      const float e = __expf(sv - mx);
      float sum = e;
#pragma unroll
      for (int m = 1; m < 16; m <<= 1) sum += __shfl_xor(sum, m);
      sc[i16 * FSTR + j16] = e / sum;
    }
    __syncthreads();
    {
      float2 acc[4] = {{0, 0}, {0, 0}, {0, 0}, {0, 0}};
      mm_acc(fT, Wv, rbase, c0, acc); store_cols(bufA, rbase, c0, acc);
    }
    __syncthreads();
    {
      // f += a @ v
      float va[16], vb[16];
#pragma unroll
      for (int jj = 0; jj < 16; jj += 4) {
        const float4 a4 = *(const float4*)(bufA + c0 * FSTR + jj);
        const float4 b4 = *(const float4*)(bufA + (c0 + 1) * FSTR + jj);
        va[jj] = a4.x; va[jj + 1] = a4.y; va[jj + 2] = a4.z; va[jj + 3] = a4.w;
        vb[jj] = b4.x; vb[jj + 1] = b4.y; vb[jj + 2] = b4.z; vb[jj + 3] = b4.w;
      }
      float2 fn[4];
#pragma unroll
      for (int r = 0; r < 4; ++r) {
        const int i = rbase + r;
        float ax = fT[c0 * FSTR + i], ay = fT[(c0 + 1) * FSTR + i];
#pragma unroll
        for (int jj = 0; jj < 16; ++jj) {
          const float a = sc[i * FSTR + jj];
          ax += a * va[jj]; ay += a * vb[jj];
        }
        fn[r].x = ax; fn[r].y = ay;
      }
      __syncthreads();
      store_cols(fT, rbase, c0, fn);
    }
    __syncthreads();
  }

  // ---- feat = max over neighbors of (f @ wout + bout) ----
  {
    float2 acc[4] = {{0, 0}, {0, 0}, {0, 0}, {0, 0}};
    mm_acc(fT, wout, rbase, c0, acc);
    const float2 bo = *(const float2*)(bout + c0);
    float mxx = acc[0].x + bo.x, mxy = acc[0].y + bo.y;
#pragma unroll
    for (int r = 1; r < 4; ++r) {
      mxx = fmaxf(mxx, acc[r].x + bo.x); mxy = fmaxf(mxy, acc[r].y + bo.y);
    }
    featp[wave * CDIM + c0] = mxx; featp[wave * CDIM + c0 + 1] = mxy;
  }
  __syncthreads();
  if (t < CDIM) {
    float m = featp[t];
    m = fmaxf(m, featp[CDIM + t]);
    m = fmaxf(m, featp[2 * CDIM + t]);
    m = fmaxf(m, featp[3 * CDIM + t]);
    featp[t] = m;
  }
  __syncthreads();
  if (t < 64) {
    float a = ms_b1[t];
#pragma unroll 4
    for (int c = 0; c < CDIM; ++c) a += featp[c] * ms_w1[c * 64 + t];
    h1s[t] = fmaxf(a, 0.f);
  }
  __syncthreads();
  if (t < 16) {
    float a = ms_b2[t];
#pragma unroll 4
    for (int c = 0; c < 64; ++c) a += h1s[c] * ms_w2[c * 16 + t];
    h2s[t] = fmaxf(a, 0.f);
  }
  __syncthreads();
  if (t == 0) {
    float mu = ms_b3[0], lg = ms_b3[1];
#pragma unroll
    for (int c = 0; c < 16; ++c) {
      mu += h2s[c] * ms_w3[c * 2]; lg += h2s[c] * ms_w3[c * 2 + 1];
    }
    const float sigma = expf(lg);
    const float inv = 1.f / (sigma * 1.41421356237309504880f);
    const float ta = ((const float*)bx)[trow * 4 + 3];
    const float p = 0.5f * (erff((ta + 0.5f - mu) * inv) - erff((ta - 0.5f - mu) * inv));
    float bits = -log2f(p + 1e-10f);
    bits = fminf(fmaxf(bits, 0.f), 50.f);
    atomicAdd(out, bits);
  }
}

// ---------------------------------------------------------------------------
extern "C" void kernel_launch(void* const* d_in, const int* in_sizes, int n_in,
                              void* d_out, int out_size, void* d_ws, size_t ws_size,
                              hipStream_t stream) {
  const float4* bx      = (const float4*)d_in[0];
  const float*  attr_w  = (const float*)d_in[1];
  const float*  attr_b  = (const float*)d_in[2];
  const float*  pos_w1  = (const float*)d_in[3];
  const float*  pos_b1  = (const float*)d_in[4];
  const float*  pos_w2  = (const float*)d_in[5];
  const float*  pos_b2  = (const float*)d_in[6];
  const float*  wq      = (const float*)d_in[7];
  const float*  wk      = (const float*)d_in[8];
  const float*  wv      = (const float*)d_in[9];
  const float*  wout    = (const float*)d_in[10];
  const float*  bout    = (const float*)d_in[11];
  const float*  ms_w1   = (const float*)d_in[12];
  const float*  ms_b1   = (const float*)d_in[13];
  const float*  ms_w2   = (const float*)d_in[14];
  const float*  ms_b2   = (const float*)d_in[15];
  const float*  ms_w3   = (const float*)d_in[16];
  const float*  ms_b3   = (const float*)d_in[17];
  float* out   = (float*)d_out;
  int* idx_ws  = (int*)d_ws;   // NTGT*16 ints = 896KB

  hipMemsetAsync(d_out, 0, sizeof(float), stream);
  knn_kernel<<<NWIN * 64, 256, 0, stream>>>(bx, idx_ws);
  nn_kernel<<<NTGT, 256, 0, stream>>>(bx, idx_ws, attr_w, attr_b, pos_w1, pos_b1,
                                      pos_w2, pos_b2, wq, wk, wv, wout, bout,
                                      ms_w1, ms_b1, ms_w2, ms_b2, ms_w3, ms_b3, out);
}

// Round 2
// 1399.642 us; speedup vs baseline: 2.8335x; 2.8335x over previous
//
#include <hip/hip_runtime.h>
#include <math.h>

#define NPTS 16384
#define WWIN 2048
#define NWIN 7
#define KNB  16
#define CDIM 128
#define NTGT (NPTS - WWIN)   // 14336
#define TPB  4               // targets per nn block (M = 64 rows)

typedef _Float16 f16;
typedef __attribute__((ext_vector_type(8))) _Float16 f16x8;
typedef __attribute__((ext_vector_type(4))) _Float16 f16x4;
typedef __attribute__((ext_vector_type(2))) _Float16 f16x2;
typedef __attribute__((ext_vector_type(4))) float f32x4;

#define MFMA16(a, b, c) __builtin_amdgcn_mfma_f32_16x16x32_f16((a), (b), (c), 0, 0, 0)

// ---------------------------------------------------------------------------
// KNN: exact top-16 nearest context points per target (unchanged from R0).
// ---------------------------------------------------------------------------
__global__ __launch_bounds__(256, 4) void knn_kernel(const float4* __restrict__ bx,
                                                     int* __restrict__ idx_ws) {
  __shared__ float4 stage[2048];
  float2* pairs = (float2*)stage;

  const int w    = blockIdx.x >> 6;
  const int bg   = blockIdx.x & 63;
  const int cur  = WWIN * (w + 1);
  const int t    = threadIdx.x;
  const int s    = t >> 5;
  const int tl   = t & 31;
  const int trow = cur + bg * 32 + tl;

  const float4 tp = bx[trow];

  float sd[KNB];
  int   si[KNB];
#pragma unroll
  for (int q = 0; q < KNB; ++q) { sd[q] = 3.4e38f; si[q] = -1; }

  for (int ch = 0; ch <= w; ++ch) {
    __syncthreads();
    for (int q = t; q < 2048; q += 256) stage[q] = bx[ch * 2048 + q];
    __syncthreads();
    for (int j = s; j < 2048; j += 8) {
      const float4 cp = stage[j];
      const float dx = tp.x - cp.x, dy = tp.y - cp.y, dz = tp.z - cp.z;
      const float d2 = dx * dx + dy * dy + dz * dz;
      if (d2 < sd[KNB - 1]) {
        float cv = d2; int ci = ch * 2048 + j;
#pragma unroll
        for (int q = 0; q < KNB; ++q) {
          const bool lt = cv < sd[q];
          const float nv = lt ? cv : sd[q];
          const float xv = lt ? sd[q] : cv;
          const int   ni = lt ? ci : si[q];
          const int   xi = lt ? si[q] : ci;
          sd[q] = nv; si[q] = ni; cv = xv; ci = xi;
        }
      }
    }
  }
  __syncthreads();
#pragma unroll
  for (int q = 0; q < KNB; ++q)
    pairs[(tl * 8 + s) * KNB + q] = make_float2(sd[q], __int_as_float(si[q]));
  __syncthreads();

  if (t < 32) {
    int h0 = 0, h1 = 0, h2 = 0, h3 = 0, h4 = 0, h5 = 0, h6 = 0, h7 = 0;
    const int slot = cur + bg * 32 + t - WWIN;
    const int base = t * 8 * KNB;
    for (int n = 0; n < KNB; ++n) {
      float best = 3.5e38f; int baddr = base; int bs = 0;
      {
        int hh, ad; float v;
#define TRY(S, H) hh = H; if (hh < KNB) { ad = base + (S)*KNB + hh; v = pairs[ad].x; \
                  if (v < best) { best = v; baddr = ad; bs = (S); } }
        TRY(0, h0) TRY(1, h1) TRY(2, h2) TRY(3, h3)
        TRY(4, h4) TRY(5, h5) TRY(6, h6) TRY(7, h7)
#undef TRY
      }
      idx_ws[slot * KNB + n] = __float_as_int(pairs[baddr].y);
      h0 += (bs == 0); h1 += (bs == 1); h2 += (bs == 2); h3 += (bs == 3);
      h4 += (bs == 4); h5 += (bs == 5); h6 += (bs == 6); h7 += (bs == 7);
    }
  }
}

// ---------------------------------------------------------------------------
// Weight prep: f16 + transpose -> wt[mat][n][k], mat order:
//   0 = pos_w2, 1..5 = wq[l], 6..10 = wk[l], 11..15 = wv[l], 16 = wout
// ---------------------------------------------------------------------------
__global__ void prep_kernel(const float* __restrict__ pos_w2,
                            const float* __restrict__ wq,
                            const float* __restrict__ wk,
                            const float* __restrict__ wv,
                            const float* __restrict__ wout,
                            f16* __restrict__ wt) {
  const int i = blockIdx.x * 256 + threadIdx.x;   // 17*16384 total
  if (i >= 17 * 16384) return;
  const int mat = i >> 14;
  const int e   = i & 16383;
  const int k   = e >> 7;
  const int n   = e & 127;
  const float* src;
  if (mat == 0)       src = pos_w2;
  else if (mat <= 5)  src = wq + (mat - 1) * 16384;
  else if (mat <= 10) src = wk + (mat - 6) * 16384;
  else if (mat <= 15) src = wv + (mat - 11) * 16384;
  else                src = wout;
  wt[mat * 16384 + n * 128 + k] = (f16)src[k * 128 + n];
}

// ---------------------------------------------------------------------------
// nn kernel: MFMA f16. 4 targets/block, 256 thr = 4 waves; wave wv owns
// output cols [32*wv, 32*wv+32). f/Q/K in LDS f16, XOR-swizzled rows.
// ---------------------------------------------------------------------------
__global__ __launch_bounds__(256, 3) void nn_kernel(
    const float4* __restrict__ bx, const int* __restrict__ idx_ws,
    const f16* __restrict__ wt,
    const float* __restrict__ attr_w, const float* __restrict__ attr_b,
    const float* __restrict__ pos_w1, const float* __restrict__ pos_b1,
    const float* __restrict__ pos_b2, const float* __restrict__ bout,
    const float* __restrict__ ms_w1, const float* __restrict__ ms_b1,
    const float* __restrict__ ms_w2, const float* __restrict__ ms_b2,
    const float* __restrict__ ms_w3, const float* __restrict__ ms_b3,
    float* __restrict__ partials) {
  __shared__ __align__(16) f16 fA[64 * 128];   // 16KB  f, A-layout, swizzled
  __shared__ __align__(16) f16 qA[64 * 128];   // 16KB  Q / Vt[128][64] / prologue gg
  __shared__ __align__(16) f16 kA[64 * 128];   // 16KB  K / pos1 buffer
  __shared__ __align__(16) f16 pA[TPB * 512];  // 4KB   P [4][16][32] / epilogue f32 overlay

  const int t    = threadIdx.x;
  const int wv   = t >> 6;
  const int lane = t & 63;
  const int l15  = lane & 15;
  const int lg   = lane >> 4;
  const int n0   = wv * 32;
  const int slot0 = blockIdx.x * TPB;

  // ---- helpers ----
  auto ldA = [&](const f16* buf, int mt, int kc) -> f16x8 {
    const int row = mt * 16 + l15;
    const int col = (kc * 32 + lg * 8) ^ ((row & 7) << 3);
    return *(const f16x8*)(buf + row * 128 + col);
  };
  auto ldB = [&](int mat, int nn, int kc) -> f16x8 {
    return *(const f16x8*)(wt + mat * 16384 + (nn + l15) * 128 + kc * 32 + lg * 8);
  };
  auto stD = [&](f16* buf, int mt, int nt, const f32x4 v) {
#pragma unroll
    for (int r = 0; r < 4; ++r) {
      const int row = mt * 16 + lg * 4 + r;
      const int col = (n0 + nt * 16 + l15) ^ ((row & 7) << 3);
      buf[row * 128 + col] = (f16)v[r];
    }
  };
  auto gemm = [&](const f16* src, int mat, f32x4 acc[4][2]) {
#pragma unroll
    for (int kc = 0; kc < 4; ++kc) {
      const f16x8 b0 = ldB(mat, n0, kc);
      const f16x8 b1 = ldB(mat, n0 + 16, kc);
#pragma unroll
      for (int mt = 0; mt < 4; ++mt) {
        const f16x8 a = ldA(src, mt, kc);
        acc[mt][0] = MFMA16(a, b0, acc[mt][0]);
        acc[mt][1] = MFMA16(a, b1, acc[mt][1]);
      }
    }
  };

  // ---- zero P padding (cols 16..31 stay zero forever) ----
  for (int i = t; i < TPB * 512; i += 256) pA[i] = (f16)0.f;

  // ---- gather 16 neighbors per target, center + max-norm (wave 0) ----
  float* ggs = (float*)qA;   // [64][4]: gx,gy,gz,ga  (overlay; qA free until layer 1)
  if (t < 64) {
    const int nid  = idx_ws[(slot0 + (t >> 4)) * KNB + (t & 15)];
    const float4 p = bx[nid];
    float sx = p.x, sy = p.y, sz = p.z;
#pragma unroll
    for (int m = 1; m < 16; m <<= 1) {
      sx += __shfl_xor(sx, m); sy += __shfl_xor(sy, m); sz += __shfl_xor(sz, m);
    }
    const float gx = p.x - sx * 0.0625f;
    const float gy = p.y - sy * 0.0625f;
    const float gz = p.z - sz * 0.0625f;
    float nr = sqrtf(gx * gx + gy * gy + gz * gz);
#pragma unroll
    for (int m = 1; m < 16; m <<= 1) nr = fmaxf(nr, __shfl_xor(nr, m));
    const float inv = 1.f / fmaxf(nr, 1e-8f);
    ggs[t * 4 + 0] = gx * inv; ggs[t * 4 + 1] = gy * inv;
    ggs[t * 4 + 2] = gz * inv; ggs[t * 4 + 3] = p.w;
  }
  __syncthreads();

  // ---- pos1 = relu(gg @ pos_w1 + b1) -> kA (A-layout f16) ----
  {
    const int row = t & 63;
    const int cb  = (t >> 6) * 32;
    const float gx = ggs[row * 4], gy = ggs[row * 4 + 1], gz = ggs[row * 4 + 2];
#pragma unroll
    for (int c = cb; c < cb + 32; c += 2) {
      float h0 = pos_b1[c]     + gx * pos_w1[c]     + gy * pos_w1[128 + c]     + gz * pos_w1[256 + c];
      float h1 = pos_b1[c + 1] + gx * pos_w1[c + 1] + gy * pos_w1[128 + c + 1] + gz * pos_w1[256 + c + 1];
      f16x2 pr; pr[0] = (f16)fmaxf(h0, 0.f); pr[1] = (f16)fmaxf(h1, 0.f);
      *(f16x2*)(kA + row * 128 + (c ^ ((row & 7) << 3))) = pr;
    }
  }
  __syncthreads();

  // ---- f0 = pos1 @ pos_w2^T + b2 + ga*attr_w + attr_b -> fA ----
  {
    f32x4 acc[4][2];
#pragma unroll
    for (int mt = 0; mt < 4; ++mt)
#pragma unroll
      for (int nt = 0; nt < 2; ++nt) acc[mt][nt] = (f32x4){0.f, 0.f, 0.f, 0.f};
    gemm(kA, 0, acc);
#pragma unroll
    for (int nt = 0; nt < 2; ++nt) {
      const int col = n0 + nt * 16 + l15;
      const float bias = pos_b2[col] + attr_b[col];
      const float aw   = attr_w[col];
#pragma unroll
      for (int mt = 0; mt < 4; ++mt) {
        f32x4 v = acc[mt][nt];
#pragma unroll
        for (int r = 0; r < 4; ++r)
          v[r] += bias + ggs[(mt * 16 + lg * 4 + r) * 4 + 3] * aw;
        stD(fA, mt, nt, v);
      }
    }
  }
  __syncthreads();

  // ---- 5 attention layers ----
  for (int l = 0; l < 5; ++l) {
    {  // Q -> qA, K -> kA
      f32x4 acc[4][2];
#pragma unroll
      for (int mt = 0; mt < 4; ++mt)
#pragma unroll
        for (int nt = 0; nt < 2; ++nt) acc[mt][nt] = (f32x4){0.f, 0.f, 0.f, 0.f};
      gemm(fA, 1 + l, acc);
#pragma unroll
      for (int mt = 0; mt < 4; ++mt)
#pragma unroll
        for (int nt = 0; nt < 2; ++nt) stD(qA, mt, nt, acc[mt][nt]);
#pragma unroll
      for (int mt = 0; mt < 4; ++mt)
#pragma unroll
        for (int nt = 0; nt < 2; ++nt) acc[mt][nt] = (f32x4){0.f, 0.f, 0.f, 0.f};
      gemm(fA, 6 + l, acc);
#pragma unroll
      for (int mt = 0; mt < 4; ++mt)
#pragma unroll
        for (int nt = 0; nt < 2; ++nt) stD(kA, mt, nt, acc[mt][nt]);
    }
    __syncthreads();
    {  // scores for target wv: S = Q_t K_t^T, softmax, P -> pA
      f32x4 s = (f32x4){0.f, 0.f, 0.f, 0.f};
#pragma unroll
      for (int kc = 0; kc < 4; ++kc)
        s = MFMA16(ldA(qA, wv, kc), ldA(kA, wv, kc), s);
#pragma unroll
      for (int r = 0; r < 4; ++r) {
        float v = s[r] * 0.08838834764831844055f;
        float mx = v;
#pragma unroll
        for (int m = 1; m < 16; m <<= 1) mx = fmaxf(mx, __shfl_xor(mx, m));
        const float e = __expf(v - mx);
        float sm = e;
#pragma unroll
        for (int m = 1; m < 16; m <<= 1) sm += __shfl_xor(sm, m);
        pA[wv * 512 + (lg * 4 + r) * 32 + l15] = (f16)(e / sm);
      }
    }
    __syncthreads();
    f16* vt = qA;   // Vt[128][64], reuses Q buffer
    {  // V -> Vt (transposed, swizzled on ch)
      f32x4 acc[4][2];
#pragma unroll
      for (int mt = 0; mt < 4; ++mt)
#pragma unroll
        for (int nt = 0; nt < 2; ++nt) acc[mt][nt] = (f32x4){0.f, 0.f, 0.f, 0.f};
      gemm(fA, 11 + l, acc);
#pragma unroll
      for (int mt = 0; mt < 4; ++mt)
#pragma unroll
        for (int nt = 0; nt < 2; ++nt) {
          const int ch = n0 + nt * 16 + l15;
          const int r0 = (mt * 16 + lg * 4) ^ ((ch & 7) << 3);
          f16x4 p;
#pragma unroll
          for (int r = 0; r < 4; ++r) p[r] = (f16)acc[mt][nt][r];
          *(f16x4*)(vt + ch * 64 + r0) = p;
        }
    }
    __syncthreads();
    {  // f += P @ V  (own col slice; C-operand = current f)
#pragma unroll
      for (int tt = 0; tt < 4; ++tt) {
        const f16x8 a = *(const f16x8*)(pA + tt * 512 + l15 * 32 + lg * 8);
#pragma unroll
        for (int nt = 0; nt < 2; ++nt) {
          const int colb = n0 + nt * 16 + l15;
          f32x4 c;
#pragma unroll
          for (int r = 0; r < 4; ++r) {
            const int row = tt * 16 + lg * 4 + r;
            c[r] = (float)fA[row * 128 + (colb ^ ((row & 7) << 3))];
          }
          const int ch = colb;
          const int r0 = (tt * 16 + 8 * (lg & 1)) ^ ((ch & 7) << 3);
          const f16x8 b = *(const f16x8*)(vt + ch * 64 + r0);
          c = MFMA16(a, b, c);
          stD(fA, tt, nt, c);
        }
      }
    }
    __syncthreads();
  }

  // ---- feature head: feat = max_rows(f @ wout + bout) per target ----
  float* feats = (float*)pA;          // [4][128] f32 overlay (pA done)
  float* h1s   = feats + 512;         // [4][64]
  float* h2s   = h1s + 256;           // [4][16]
  float* btmp  = h2s + 64;            // [4]
  {
    f32x4 acc[4][2];
#pragma unroll
    for (int mt = 0; mt < 4; ++mt)
#pragma unroll
      for (int nt = 0; nt < 2; ++nt) acc[mt][nt] = (f32x4){0.f, 0.f, 0.f, 0.f};
    gemm(fA, 16, acc);
#pragma unroll
    for (int nt = 0; nt < 2; ++nt) {
      const int col = n0 + nt * 16 + l15;
      const float bo = bout[col];
#pragma unroll
      for (int mt = 0; mt < 4; ++mt) {
        const f32x4 v = acc[mt][nt];
        float m = fmaxf(fmaxf(v[0], v[1]), fmaxf(v[2], v[3])) + bo;
        m = fmaxf(m, __shfl_xor(m, 16));
        m = fmaxf(m, __shfl_xor(m, 32));
        if (lg == 0) feats[mt * 128 + col] = m;
      }
    }
  }
  __syncthreads();
  {  // h1 = relu(feat @ ms_w1 + b1): 4 targets x 64
    const int tt = t >> 6, h = t & 63;
    float a = ms_b1[h];
#pragma unroll 4
    for (int c = 0; c < 128; ++c) a += feats[tt * 128 + c] * ms_w1[c * 64 + h];
    h1s[tt * 64 + h] = fmaxf(a, 0.f);
  }
  __syncthreads();
  if (t < 64) {
    const int tt = t >> 4, h = t & 15;
    float a = ms_b2[h];
#pragma unroll 4
    for (int c = 0; c < 64; ++c) a += h1s[tt * 64 + c] * ms_w2[c * 16 + h];
    h2s[tt * 16 + h] = fmaxf(a, 0.f);
  }
  __syncthreads();
  if (t < TPB) {
    float mu = ms_b3[0], lgs = ms_b3[1];
#pragma unroll
    for (int c = 0; c < 16; ++c) {
      mu  += h2s[t * 16 + c] * ms_w3[2 * c];
      lgs += h2s[t * 16 + c] * ms_w3[2 * c + 1];
    }
    const float sigma = expf(lgs);
    const float inv   = 1.f / (sigma * 1.41421356237309504880f);
    const float ta    = ((const float*)bx)[(WWIN + slot0 + t) * 4 + 3];
    const float p = 0.5f * (erff((ta + 0.5f - mu) * inv) - erff((ta - 0.5f - mu) * inv));
    float bits = -log2f(p + 1e-10f);
    btmp[t] = fminf(fmaxf(bits, 0.f), 50.f);
  }
  __syncthreads();
  if (t == 0) partials[blockIdx.x] = btmp[0] + btmp[1] + btmp[2] + btmp[3];
}

// ---------------------------------------------------------------------------
__global__ void reduce_kernel(const float* __restrict__ partials, float* __restrict__ out) {
  float s = 0.f;
  for (int i = threadIdx.x; i < NTGT / TPB; i += 256) s += partials[i];
#pragma unroll
  for (int m = 1; m < 64; m <<= 1) s += __shfl_xor(s, m);
  __shared__ float wsum[4];
  if ((threadIdx.x & 63) == 0) wsum[threadIdx.x >> 6] = s;
  __syncthreads();
  if (threadIdx.x == 0) out[0] = wsum[0] + wsum[1] + wsum[2] + wsum[3];
}

// ---------------------------------------------------------------------------
extern "C" void kernel_launch(void* const* d_in, const int* in_sizes, int n_in,
                              void* d_out, int out_size, void* d_ws, size_t ws_size,
                              hipStream_t stream) {
  const float4* bx     = (const float4*)d_in[0];
  const float* attr_w  = (const float*)d_in[1];
  const float* attr_b  = (const float*)d_in[2];
  const float* pos_w1  = (const float*)d_in[3];
  const float* pos_b1  = (const float*)d_in[4];
  const float* pos_w2  = (const float*)d_in[5];
  const float* pos_b2  = (const float*)d_in[6];
  const float* wq      = (const float*)d_in[7];
  const float* wk      = (const float*)d_in[8];
  const float* wv      = (const float*)d_in[9];
  const float* wout    = (const float*)d_in[10];
  const float* bout    = (const float*)d_in[11];
  const float* ms_w1   = (const float*)d_in[12];
  const float* ms_b1   = (const float*)d_in[13];
  const float* ms_w2   = (const float*)d_in[14];
  const float* ms_b2   = (const float*)d_in[15];
  const float* ms_w3   = (const float*)d_in[16];
  const float* ms_b3   = (const float*)d_in[17];

  int*   idx_ws   = (int*)d_ws;                                   // 896KB @ 0
  f16*   wt       = (f16*)((char*)d_ws + (1 << 20));              // 544KB @ 1MB
  float* partials = (float*)((char*)d_ws + (1 << 20) + 17 * 16384 * 2);

  prep_kernel<<<(17 * 16384 + 255) / 256, 256, 0, stream>>>(pos_w2, wq, wk, wv, wout, wt);
  knn_kernel<<<NWIN * 64, 256, 0, stream>>>(bx, idx_ws);
  nn_kernel<<<NTGT / TPB, 256, 0, stream>>>(bx, idx_ws, wt, attr_w, attr_b,
                                            pos_w1, pos_b1, pos_b2, bout,
                                            ms_w1, ms_b1, ms_w2, ms_b2, ms_w3, ms_b3,
                                            partials);
  reduce_kernel<<<1, 256, 0, stream>>>(partials, (float*)d_out);
}

// Round 3
// 738.823 us; speedup vs baseline: 5.3678x; 1.8944x over previous
//
#include <hip/hip_runtime.h>
#include <math.h>

#define NPTS 16384
#define WWIN 2048
#define NWIN 7
#define KNB  16
#define CDIM 128
#define NTGT (NPTS - WWIN)   // 14336
#define TPB  4               // targets per nn block (M = 64 rows)
#define NMAT 12              // 0=pos_w2, 1..5=Wv, 6=wout, 7..11=Mw(=Wq Wk^T)

typedef _Float16 f16;
typedef __attribute__((ext_vector_type(8))) _Float16 f16x8;
typedef __attribute__((ext_vector_type(4))) _Float16 f16x4;
typedef __attribute__((ext_vector_type(2))) _Float16 f16x2;
typedef __attribute__((ext_vector_type(4))) float f32x4;

#define MFMA16(a, b, c) __builtin_amdgcn_mfma_f32_16x16x32_f16((a), (b), (c), 0, 0, 0)

// ---------------------------------------------------------------------------
// KNN part 1: uniform blocks. block = (window w, target-group bg, chunk ch).
// 256 thr = 8 scanners x 32 targets; exact top-16 of this chunk per target,
// written as sorted (d, idx) lists to part[].
// ---------------------------------------------------------------------------
__global__ __launch_bounds__(256, 4) void knn_part(const float4* __restrict__ bx,
                                                   float2* __restrict__ part) {
  __shared__ float4 stage[2048];
  float2* pairs = (float2*)stage;               // overlay after scan

  int bid = blockIdx.x, w = 0, base = 0;
  while (bid >= base + 64 * (w + 1)) { base += 64 * (w + 1); ++w; }
  const int rem = bid - base;
  const int bg  = rem / (w + 1);
  const int ch  = rem % (w + 1);

  const int cur  = WWIN * (w + 1);
  const int t    = threadIdx.x;
  const int s    = t >> 5;
  const int tl   = t & 31;
  const int trow = cur + bg * 32 + tl;

  const float4 tp = bx[trow];

  float sd[KNB];
  int   si[KNB];
#pragma unroll
  for (int q = 0; q < KNB; ++q) { sd[q] = 3.4e38f; si[q] = -1; }

  for (int q = t; q < 2048; q += 256) stage[q] = bx[ch * 2048 + q];
  __syncthreads();
  for (int j = s; j < 2048; j += 8) {
    const float4 cp = stage[j];
    const float dx = tp.x - cp.x, dy = tp.y - cp.y, dz = tp.z - cp.z;
    const float d2 = dx * dx + dy * dy + dz * dz;
    if (d2 < sd[KNB - 1]) {
      float cv = d2; int ci = ch * 2048 + j;
#pragma unroll
      for (int q = 0; q < KNB; ++q) {
        const bool lt = cv < sd[q];
        const float nv = lt ? cv : sd[q];
        const float xv = lt ? sd[q] : cv;
        const int   ni = lt ? ci : si[q];
        const int   xi = lt ? si[q] : ci;
        sd[q] = nv; si[q] = ni; cv = xv; ci = xi;
      }
    }
  }
  __syncthreads();
#pragma unroll
  for (int q = 0; q < KNB; ++q)
    pairs[(tl * 8 + s) * KNB + q] = make_float2(sd[q], __int_as_float(si[q]));
  __syncthreads();

  if (t < 32) {   // 8-way merge -> chunk top-16 for target t
    int h0 = 0, h1 = 0, h2 = 0, h3 = 0, h4 = 0, h5 = 0, h6 = 0, h7 = 0;
    const int slot = cur + bg * 32 + t - WWIN;
    const int base2 = t * 8 * KNB;
    float2* dst = part + (size_t)(slot * 7 + ch) * KNB;
    for (int n = 0; n < KNB; ++n) {
      float best = 3.5e38f; int baddr = base2; int bs = 0;
      {
        int hh, ad; float v;
#define TRY(S, H) hh = H; if (hh < KNB) { ad = base2 + (S)*KNB + hh; v = pairs[ad].x; \
                  if (v < best) { best = v; baddr = ad; bs = (S); } }
        TRY(0, h0) TRY(1, h1) TRY(2, h2) TRY(3, h3)
        TRY(4, h4) TRY(5, h5) TRY(6, h6) TRY(7, h7)
#undef TRY
      }
      dst[n] = pairs[baddr];
      h0 += (bs == 0); h1 += (bs == 1); h2 += (bs == 2); h3 += (bs == 3);
      h4 += (bs == 4); h5 += (bs == 5); h6 += (bs == 6); h7 += (bs == 7);
    }
  }
}

// ---------------------------------------------------------------------------
// KNN part 2: merge per-chunk sorted lists -> final 16 neighbor indices.
// ---------------------------------------------------------------------------
__global__ void knn_merge(const float2* __restrict__ part, int* __restrict__ idx_ws) {
  const int slot = blockIdx.x * 256 + threadIdx.x;
  if (slot >= NTGT) return;
  const int nch = (slot >> 11) + 1;
  const float2* base = part + (size_t)slot * 7 * KNB;
  int h[7] = {0, 0, 0, 0, 0, 0, 0};
  for (int n = 0; n < KNB; ++n) {
    float best = 3.5e38f; int bc = 0;
    for (int c = 0; c < nch; ++c) {
      if (h[c] < KNB) {
        const float v = base[c * KNB + h[c]].x;
        if (v < best) { best = v; bc = c; }
      }
    }
    idx_ws[slot * KNB + n] = __float_as_int(base[bc * KNB + h[bc]].y);
    ++h[bc];
  }
}

// ---------------------------------------------------------------------------
// Weight prep -> wt[mat][n][k] f16 (B-operand layout).
//   mat 0 = pos_w2^T, 1..5 = Wv^T, 6 = wout^T, 7..11 = (Wq Wk^T)^T
// ---------------------------------------------------------------------------
__global__ void prep_kernel(const float* __restrict__ pos_w2,
                            const float* __restrict__ wq,
                            const float* __restrict__ wk,
                            const float* __restrict__ wv,
                            const float* __restrict__ wout,
                            f16* __restrict__ wt) {
  const int i = blockIdx.x * 256 + threadIdx.x;
  if (i >= NMAT * 16384) return;
  const int mat = i >> 14;
  const int e   = i & 16383;
  const int k   = e >> 7;
  const int n   = e & 127;
  if (mat < 7) {
    const float* src = (mat == 0) ? pos_w2 : (mat <= 5 ? wv + (mat - 1) * 16384 : wout);
    wt[mat * 16384 + n * 128 + k] = (f16)src[k * 128 + n];
  } else {
    const int l = mat - 7;
    const float* qr = wq + l * 16384 + k * 128;   // row k of Wq
    const float* kr = wk + l * 16384 + n * 128;   // row n of Wk
    float sacc = 0.f;
#pragma unroll 4
    for (int c = 0; c < 128; ++c) sacc += qr[c] * kr[c];
    wt[mat * 16384 + n * 128 + k] = (f16)sacc;    // Mw[k][n] in [n][k] layout
  }
}

// ---------------------------------------------------------------------------
// nn kernel helpers (free __forceinline__ functions -> full SROA to regs)
// ---------------------------------------------------------------------------
__device__ __forceinline__ f16x8 ldA(const f16* __restrict__ buf, int l15, int lg,
                                     int mt, int kc) {
  const int row = mt * 16 + l15;
  const int col = (kc * 32 + lg * 8) ^ ((row & 7) << 3);
  return *(const f16x8*)(buf + row * 128 + col);
}

__device__ __forceinline__ void stD(f16* __restrict__ buf, int l15, int lg, int n0,
                                    int mt, int nt, const f32x4 v) {
#pragma unroll
  for (int r = 0; r < 4; ++r) {
    const int row = mt * 16 + lg * 4 + r;
    const int col = (n0 + nt * 16 + l15) ^ ((row & 7) << 3);
    buf[row * 128 + col] = (f16)v[r];
  }
}

__device__ __forceinline__ void zacc(f32x4 (&acc)[4][2]) {
#pragma unroll
  for (int mt = 0; mt < 4; ++mt)
#pragma unroll
    for (int nt = 0; nt < 2; ++nt) acc[mt][nt] = (f32x4){0.f, 0.f, 0.f, 0.f};
}

__device__ __forceinline__ void gemm_tile(const f16* __restrict__ src,
                                          const f16* __restrict__ wmat,
                                          int l15, int lg, int n0,
                                          f32x4 (&acc)[4][2]) {
#pragma unroll
  for (int kc = 0; kc < 4; ++kc) {
    const f16x8 b0 = *(const f16x8*)(wmat + (n0 + l15) * 128 + kc * 32 + lg * 8);
    const f16x8 b1 = *(const f16x8*)(wmat + (n0 + 16 + l15) * 128 + kc * 32 + lg * 8);
#pragma unroll
    for (int mt = 0; mt < 4; ++mt) {
      const f16x8 a = ldA(src, l15, lg, mt, kc);
      acc[mt][0] = MFMA16(a, b0, acc[mt][0]);
      acc[mt][1] = MFMA16(a, b1, acc[mt][1]);
    }
  }
}

// ---------------------------------------------------------------------------
// nn kernel: 4 targets/block, 256 thr = 4 waves; wave wv owns cols
// [32*wv, 32*wv+32). LDS: fA (f), qA (pos1 / G / Vt), pA (P + overlays).
// ---------------------------------------------------------------------------
__global__ __launch_bounds__(256, 3) void nn_kernel(
    const float4* __restrict__ bx, const int* __restrict__ idx_ws,
    const f16* __restrict__ wt,
    const float* __restrict__ attr_w, const float* __restrict__ attr_b,
    const float* __restrict__ pos_w1, const float* __restrict__ pos_b1,
    const float* __restrict__ pos_b2, const float* __restrict__ bout,
    const float* __restrict__ ms_w1, const float* __restrict__ ms_b1,
    const float* __restrict__ ms_w2, const float* __restrict__ ms_b2,
    const float* __restrict__ ms_w3, const float* __restrict__ ms_b3,
    float* __restrict__ partials) {
  __shared__ __align__(16) f16 fA[64 * 128];   // 16KB  f (A-layout, swizzled)
  __shared__ __align__(16) f16 qA[64 * 128];   // 16KB  pos1 / G / Vt[128][64]
  __shared__ __align__(16) f16 pA[TPB * 512];  // 4KB   ggs / P[4][16][32] / epilogue

  const int t     = threadIdx.x;
  const int wv    = t >> 6;
  const int lane  = t & 63;
  const int l15   = lane & 15;
  const int lg    = lane >> 4;
  const int n0    = wv * 32;
  const int slot0 = blockIdx.x * TPB;

  // ---- gather 16 neighbors/target, center + max-norm; ggs overlay on pA ----
  float* ggs = (float*)pA;   // [64][4]: gx,gy,gz,ga
  if (t < 64) {
    const int nid  = idx_ws[(slot0 + (t >> 4)) * KNB + (t & 15)];
    const float4 p = bx[nid];
    float sx = p.x, sy = p.y, sz = p.z;
#pragma unroll
    for (int m = 1; m < 16; m <<= 1) {
      sx += __shfl_xor(sx, m); sy += __shfl_xor(sy, m); sz += __shfl_xor(sz, m);
    }
    const float gx = p.x - sx * 0.0625f;
    const float gy = p.y - sy * 0.0625f;
    const float gz = p.z - sz * 0.0625f;
    float nr = sqrtf(gx * gx + gy * gy + gz * gz);
#pragma unroll
    for (int m = 1; m < 16; m <<= 1) nr = fmaxf(nr, __shfl_xor(nr, m));
    const float inv = 1.f / fmaxf(nr, 1e-8f);
    ggs[t * 4 + 0] = gx * inv; ggs[t * 4 + 1] = gy * inv;
    ggs[t * 4 + 2] = gz * inv; ggs[t * 4 + 3] = p.w;
  }
  __syncthreads();

  // ---- pos1 = relu(gg @ pos_w1 + b1) -> qA (A-layout f16, swizzled) ----
  {
    const int row = t & 63;
    const int cb  = (t >> 6) * 32;
    const float gx = ggs[row * 4], gy = ggs[row * 4 + 1], gz = ggs[row * 4 + 2];
#pragma unroll
    for (int c = cb; c < cb + 32; c += 2) {
      const float h0 = pos_b1[c]     + gx * pos_w1[c]     + gy * pos_w1[128 + c]     + gz * pos_w1[256 + c];
      const float h1 = pos_b1[c + 1] + gx * pos_w1[c + 1] + gy * pos_w1[128 + c + 1] + gz * pos_w1[256 + c + 1];
      f16x2 pr; pr[0] = (f16)fmaxf(h0, 0.f); pr[1] = (f16)fmaxf(h1, 0.f);
      *(f16x2*)(qA + row * 128 + (c ^ ((row & 7) << 3))) = pr;
    }
  }
  __syncthreads();

  // ---- f0 = pos1 @ pos_w2^T + b2 + ga*attr_w + attr_b -> fA ----
  {
    f32x4 acc[4][2];
    zacc(acc);
    gemm_tile(qA, wt, l15, lg, n0, acc);
#pragma unroll
    for (int nt = 0; nt < 2; ++nt) {
      const int col = n0 + nt * 16 + l15;
      const float bias = pos_b2[col] + attr_b[col];
      const float aw   = attr_w[col];
#pragma unroll
      for (int mt = 0; mt < 4; ++mt) {
        f32x4 v = acc[mt][nt];
#pragma unroll
        for (int r = 0; r < 4; ++r)
          v[r] += bias + ggs[(mt * 16 + lg * 4 + r) * 4 + 3] * aw;
        stD(fA, l15, lg, n0, mt, nt, v);
      }
    }
  }
  __syncthreads();

  // ---- zero pA (P padding cols 16..31 must stay 0) ----
  for (int i = t; i < TPB * 512; i += 256) pA[i] = (f16)0.f;
  // (no barrier needed: next pA use is after the G-store barrier below)

  // ---- 5 attention layers: S = (f @ Mw) @ f^T ----
  for (int l = 0; l < 5; ++l) {
    {  // G = f @ Mw -> qA
      f32x4 acc[4][2];
      zacc(acc);
      gemm_tile(fA, wt + (7 + l) * 16384, l15, lg, n0, acc);
#pragma unroll
      for (int mt = 0; mt < 4; ++mt)
#pragma unroll
        for (int nt = 0; nt < 2; ++nt) stD(qA, l15, lg, n0, mt, nt, acc[mt][nt]);
    }
    __syncthreads();
    {  // S = G @ f^T for target wv; softmax -> P in pA
      f32x4 s = (f32x4){0.f, 0.f, 0.f, 0.f};
#pragma unroll
      for (int kc = 0; kc < 4; ++kc)
        s = MFMA16(ldA(qA, l15, lg, wv, kc), ldA(fA, l15, lg, wv, kc), s);
#pragma unroll
      for (int r = 0; r < 4; ++r) {
        float v = s[r] * 0.08838834764831844055f;   // 1/sqrt(128)
        float mx = v;
#pragma unroll
        for (int m = 1; m < 16; m <<= 1) mx = fmaxf(mx, __shfl_xor(mx, m));
        const float e = __expf(v - mx);
        float sm = e;
#pragma unroll
        for (int m = 1; m < 16; m <<= 1) sm += __shfl_xor(sm, m);
        pA[wv * 512 + (lg * 4 + r) * 32 + l15] = (f16)(e / sm);
      }
    }
    __syncthreads();
    f16* vt = qA;   // Vt[128][64] reuses G buffer
    {  // V = f @ Wv -> Vt (transposed store, swizzled on channel)
      f32x4 acc[4][2];
      zacc(acc);
      gemm_tile(fA, wt + (1 + l) * 16384, l15, lg, n0, acc);
#pragma unroll
      for (int mt = 0; mt < 4; ++mt)
#pragma unroll
        for (int nt = 0; nt < 2; ++nt) {
          const int ch = n0 + nt * 16 + l15;
          const int r0 = (mt * 16 + lg * 4) ^ ((ch & 7) << 3);
          f16x4 p;
#pragma unroll
          for (int r = 0; r < 4; ++r) p[r] = (f16)acc[mt][nt][r];
          *(f16x4*)(vt + ch * 64 + r0) = p;
        }
    }
    __syncthreads();
    {  // f += P @ V (C-in = current f; A zero-padded for k>=16)
#pragma unroll
      for (int tt = 0; tt < 4; ++tt) {
        const f16x8 a = *(const f16x8*)(pA + tt * 512 + l15 * 32 + lg * 8);
#pragma unroll
        for (int nt = 0; nt < 2; ++nt) {
          const int colb = n0 + nt * 16 + l15;
          f32x4 c;
#pragma unroll
          for (int r = 0; r < 4; ++r) {
            const int row = tt * 16 + lg * 4 + r;
            c[r] = (float)fA[row * 128 + (colb ^ ((row & 7) << 3))];
          }
          const int r0 = (tt * 16 + 8 * (lg & 1)) ^ ((colb & 7) << 3);
          const f16x8 b = *(const f16x8*)(vt + colb * 64 + r0);
          c = MFMA16(a, b, c);
          stD(fA, l15, lg, n0, tt, nt, c);
        }
      }
    }
    __syncthreads();
  }

  // ---- feature head ----
  float* feats = (float*)pA;          // [4][128] f32 overlay
  float* h1s   = feats + 512;         // [4][64]
  float* h2s   = h1s + 256;           // [4][16]
  float* btmp  = h2s + 64;            // [4]
  {
    f32x4 acc[4][2];
    zacc(acc);
    gemm_tile(fA, wt + 6 * 16384, l15, lg, n0, acc);
#pragma unroll
    for (int nt = 0; nt < 2; ++nt) {
      const int col = n0 + nt * 16 + l15;
      const float bo = bout[col];
#pragma unroll
      for (int mt = 0; mt < 4; ++mt) {
        const f32x4 v = acc[mt][nt];
        float m = fmaxf(fmaxf(v[0], v[1]), fmaxf(v[2], v[3])) + bo;
        m = fmaxf(m, __shfl_xor(m, 16));
        m = fmaxf(m, __shfl_xor(m, 32));
        if (lg == 0) feats[mt * 128 + col] = m;
      }
    }
  }
  __syncthreads();
  {  // h1 = relu(feat @ ms_w1 + b1): 4 targets x 64
    const int tt = t >> 6, h = t & 63;
    float a = ms_b1[h];
#pragma unroll 4
    for (int c = 0; c < 128; ++c) a += feats[tt * 128 + c] * ms_w1[c * 64 + h];
    h1s[tt * 64 + h] = fmaxf(a, 0.f);
  }
  __syncthreads();
  if (t < 64) {
    const int tt = t >> 4, h = t & 15;
    float a = ms_b2[h];
#pragma unroll 4
    for (int c = 0; c < 64; ++c) a += h1s[tt * 64 + c] * ms_w2[c * 16 + h];
    h2s[tt * 16 + h] = fmaxf(a, 0.f);
  }
  __syncthreads();
  if (t < TPB) {
    float mu = ms_b3[0], lgs = ms_b3[1];
#pragma unroll
    for (int c = 0; c < 16; ++c) {
      mu  += h2s[t * 16 + c] * ms_w3[2 * c];
      lgs += h2s[t * 16 + c] * ms_w3[2 * c + 1];
    }
    const float sigma = expf(lgs);
    const float inv   = 1.f / (sigma * 1.41421356237309504880f);
    const float ta    = ((const float*)bx)[(WWIN + slot0 + t) * 4 + 3];
    const float p = 0.5f * (erff((ta + 0.5f - mu) * inv) - erff((ta - 0.5f - mu) * inv));
    float bits = -log2f(p + 1e-10f);
    btmp[t] = fminf(fmaxf(bits, 0.f), 50.f);
  }
  __syncthreads();
  if (t == 0) partials[blockIdx.x] = btmp[0] + btmp[1] + btmp[2] + btmp[3];
}

// ---------------------------------------------------------------------------
__global__ void reduce_kernel(const float* __restrict__ partials, float* __restrict__ out) {
  float s = 0.f;
  for (int i = threadIdx.x; i < NTGT / TPB; i += 256) s += partials[i];
#pragma unroll
  for (int m = 1; m < 64; m <<= 1) s += __shfl_xor(s, m);
  __shared__ float wsum[4];
  if ((threadIdx.x & 63) == 0) wsum[threadIdx.x >> 6] = s;
  __syncthreads();
  if (threadIdx.x == 0) out[0] = wsum[0] + wsum[1] + wsum[2] + wsum[3];
}

// ---------------------------------------------------------------------------
extern "C" void kernel_launch(void* const* d_in, const int* in_sizes, int n_in,
                              void* d_out, int out_size, void* d_ws, size_t ws_size,
                              hipStream_t stream) {
  const float4* bx     = (const float4*)d_in[0];
  const float* attr_w  = (const float*)d_in[1];
  const float* attr_b  = (const float*)d_in[2];
  const float* pos_w1  = (const float*)d_in[3];
  const float* pos_b1  = (const float*)d_in[4];
  const float* pos_w2  = (const float*)d_in[5];
  const float* pos_b2  = (const float*)d_in[6];
  const float* wq      = (const float*)d_in[7];
  const float* wk      = (const float*)d_in[8];
  const float* wv      = (const float*)d_in[9];
  const float* wout    = (const float*)d_in[10];
  const float* bout    = (const float*)d_in[11];
  const float* ms_w1   = (const float*)d_in[12];
  const float* ms_b1   = (const float*)d_in[13];
  const float* ms_w2   = (const float*)d_in[14];
  const float* ms_b2   = (const float*)d_in[15];
  const float* ms_w3   = (const float*)d_in[16];
  const float* ms_b3   = (const float*)d_in[17];

  int*    idx_ws   = (int*)d_ws;                                  // 896KB @ 0
  f16*    wt       = (f16*)((char*)d_ws + (1u << 20));            // 384KB @ 1MB
  float*  partials = (float*)((char*)d_ws + (3u << 19));          // 14KB  @ 1.5MB
  float2* part     = (float2*)((char*)d_ws + (2u << 20));         // 12.9MB @ 2MB

  prep_kernel<<<(NMAT * 16384 + 255) / 256, 256, 0, stream>>>(pos_w2, wq, wk, wv, wout, wt);
  knn_part<<<1792, 256, 0, stream>>>(bx, part);
  knn_merge<<<(NTGT + 255) / 256, 256, 0, stream>>>(part, idx_ws);
  nn_kernel<<<NTGT / TPB, 256, 0, stream>>>(bx, idx_ws, wt, attr_w, attr_b,
                                            pos_w1, pos_b1, pos_b2, bout,
                                            ms_w1, ms_b1, ms_w2, ms_b2, ms_w3, ms_b3,
                                            partials);
  reduce_kernel<<<1, 256, 0, stream>>>(partials, (float*)d_out);
}